// Round 7
// baseline (48.518 us; speedup 1.0000x reference)
//
#include <hip/hip_runtime.h>

#define DIM    1024
#define BATCH  8
#define QLEN   4096
#define SEQ    128
#define NMULT  2

typedef float vfloat4 __attribute__((ext_vector_type(4)));

// ---------- Kernel A ----------
// grid 1024 = m(2) x c(16 d-chunks of 64) x es(32 e-ranges of 32); 256 thr.
// vp[es][m,b,d-chunk] = sum_{e in es-range} h_last[b,e] * Wv[m,e,DIM+d]
// Each weight float4 read ONCE, feeds all 8 batches.
// Blocks with c==0 && es<8 also initialize y[m*8+es] = c_proj_b[m] (bias).
__global__ void __launch_bounds__(256) kernelA(const float* __restrict__ hidden,
                                               const float* __restrict__ c_attn_w,
                                               const float* __restrict__ c_proj_b,
                                               float* __restrict__ vp,
                                               float* __restrict__ y) {
    __shared__ float h_s[BATCH][32];
    __shared__ vfloat4 vred[16][16][9];   // [eg][d4][b], padded

    const int tid = threadIdx.x;
    const int es = blockIdx.x & 31;
    const int c  = (blockIdx.x >> 5) & 15;
    const int m  = blockIdx.x >> 9;

    if (c == 0 && es < BATCH) {            // init y row (m*8+es) with bias
        reinterpret_cast<vfloat4*>(y)[(m * BATCH + es) * 256 + tid] =
            reinterpret_cast<const vfloat4*>(c_proj_b)[m * 256 + tid];
    }

    if (tid < 64) {                        // stage h_last[b, es*32 .. +32)
        int b = tid >> 3, e4 = tid & 7;
        const vfloat4* src = reinterpret_cast<const vfloat4*>(
            hidden + (size_t)b * (SEQ * DIM) + (size_t)(SEQ - 1) * DIM + es * 32);
        reinterpret_cast<vfloat4*>(h_s[b])[e4] = src[e4];
    }
    __syncthreads();

    const int d4 = tid & 15;               // float4 of d within 64-chunk
    const int eg = tid >> 4;               // 16 e-groups of 2
    const float* wbase = c_attn_w + (size_t)m * DIM * (2 * DIM) + DIM + c * 64 + d4 * 4;

    vfloat4 acc[BATCH];
#pragma unroll
    for (int b = 0; b < BATCH; ++b) acc[b] = (vfloat4){0.f, 0.f, 0.f, 0.f};

#pragma unroll
    for (int k = 0; k < 2; ++k) {
        int el = eg * 2 + k;               // 0..31
        int e  = es * 32 + el;
        vfloat4 w4 = *reinterpret_cast<const vfloat4*>(wbase + (size_t)e * (2 * DIM));
#pragma unroll
        for (int b = 0; b < BATCH; ++b) acc[b] += h_s[b][el] * w4;
    }
#pragma unroll
    for (int b = 0; b < BATCH; ++b) vred[eg][d4][b] = acc[b];
    __syncthreads();

    if (tid < 128) {                       // reduce 16 e-groups
        int b = tid >> 4, dq = tid & 15;
        vfloat4 s = vred[0][dq][b];
#pragma unroll
        for (int g = 1; g < 16; ++g) s += vred[g][dq][b];
        reinterpret_cast<vfloat4*>(vp)[es * 4096 + (m * BATCH + b) * 256 + c * 16 + dq] = s;
    }
}

// ---------- Kernel B ----------
// grid 1024 = m(2) x cd(32 d-chunks of 32) x ce(16 e-ranges of 64); 256 thr.
// y[m,b,e] += sum_{d in cd-chunk} v[m,b,d] * Wp[m,d,e]   (atomic)
// v = c_attn_b[:,DIM:] + sum_es vp.
__global__ void __launch_bounds__(256) kernelB(const float* __restrict__ vp,
                                               const float* __restrict__ c_attn_b,
                                               const float* __restrict__ c_proj_w,
                                               float* __restrict__ y) {
    __shared__ float v_s[BATCH][32];
    __shared__ vfloat4 yred[16][16][9];    // [dg][e4][b], padded

    const int tid = threadIdx.x;
    const int ce = blockIdx.x & 15;
    const int cd = (blockIdx.x >> 4) & 31;
    const int m  = blockIdx.x >> 9;

    if (tid < 64) {                        // v_s[b][0..32) for this d-chunk
        int b = tid >> 3, d4 = tid & 7;
        vfloat4 s = reinterpret_cast<const vfloat4*>(
            c_attn_b + (size_t)m * 2 * DIM + DIM)[cd * 8 + d4];
        const vfloat4* vp4 = reinterpret_cast<const vfloat4*>(vp);
#pragma unroll
        for (int es = 0; es < 32; ++es) {
            s += vp4[es * 4096 + (m * BATCH + b) * 256 + cd * 8 + d4];
        }
        reinterpret_cast<vfloat4*>(v_s[b])[d4] = s;
    }
    __syncthreads();

    const int e4 = tid & 15;               // float4 of e within 64-e range
    const int dg = tid >> 4;               // 16 d-groups of 2
    const float* wbase = c_proj_w + (size_t)m * DIM * DIM + ce * 64 + e4 * 4;

    vfloat4 acc[BATCH];
#pragma unroll
    for (int b = 0; b < BATCH; ++b) acc[b] = (vfloat4){0.f, 0.f, 0.f, 0.f};

#pragma unroll
    for (int j = 0; j < 2; ++j) {
        int dl = dg * 2 + j;               // 0..31
        int d  = cd * 32 + dl;
        vfloat4 w4 = *reinterpret_cast<const vfloat4*>(wbase + (size_t)d * DIM);
#pragma unroll
        for (int b = 0; b < BATCH; ++b) acc[b] += v_s[b][dl] * w4;
    }
#pragma unroll
    for (int b = 0; b < BATCH; ++b) yred[dg][e4][b] = acc[b];
    __syncthreads();

    if (tid < 128) {                       // reduce 16 d-groups, atomic into y
        int b = tid >> 4, eq = tid & 15;
        vfloat4 s = yred[0][eq][b];
#pragma unroll
        for (int g = 1; g < 16; ++g) s += yred[g][eq][b];
        float* dst = y + (size_t)(m * BATCH + b) * DIM + ce * 64 + eq * 4;
        atomicAdd(dst + 0, s.x);
        atomicAdd(dst + 1, s.y);
        atomicAdd(dst + 2, s.z);
        atomicAdd(dst + 3, s.w);
    }
}

// ---------- Kernel C ----------
// 2048 blocks: b = bid>>8, q0 = (bid&255)*16; 16 q-rows per block.
// out[b,q,:] = y[0,b,:] (+ y[1,0,:] if b==0); biases already inside y.
__global__ void __launch_bounds__(256) bcast_kernel(const float* __restrict__ y,
                                                    float* __restrict__ out) {
    int b = blockIdx.x >> 8;
    int q0 = (blockIdx.x & 255) * 16;
    int t = threadIdx.x;                   // e4 = t (256 float4 = 1024 e)

    const vfloat4* y4 = reinterpret_cast<const vfloat4*>(y);
    vfloat4 val = y4[b * 256 + t];
    if (b == 0) {
        val += y4[BATCH * 256 + t];        // m=1, b=0 row
    }

    vfloat4* o = reinterpret_cast<vfloat4*>(out) + ((size_t)b * QLEN + q0) * 256 + t;
#pragma unroll
    for (int q = 0; q < 16; ++q) {
        __builtin_nontemporal_store(val, o + (size_t)q * 256);
    }
}

extern "C" void kernel_launch(void* const* d_in, const int* in_sizes, int n_in,
                              void* d_out, int out_size, void* d_ws, size_t ws_size,
                              hipStream_t stream) {
    // inputs: encoder_hidden_states, hidden_states, q_w, q_b,
    //         c_attn_w, c_attn_b, c_proj_w, c_proj_b
    const float* hidden   = (const float*)d_in[1];
    const float* c_attn_w = (const float*)d_in[4];
    const float* c_attn_b = (const float*)d_in[5];
    const float* c_proj_w = (const float*)d_in[6];
    const float* c_proj_b = (const float*)d_in[7];
    float* out = (float*)d_out;

    float* vp = (float*)d_ws;              // 32*16384 f32 = 2 MB
    float* y  = vp + 32 * 16384;           // 16384 f32 = 64 KB

    kernelA<<<1024, 256, 0, stream>>>(hidden, c_attn_w, c_proj_b, vp, y);
    kernelB<<<1024, 256, 0, stream>>>(vp, c_attn_b, c_proj_w, y);
    bcast_kernel<<<2048, 256, 0, stream>>>(y, out);
}

// Round 8
// 43.799 us; speedup vs baseline: 1.1078x; 1.1078x over previous
//
#include <hip/hip_runtime.h>

#define DIM    1024
#define BATCH  8
#define QLEN   4096
#define SEQ    128

typedef float vfloat4 __attribute__((ext_vector_type(4)));

// ---------- Fused GEMV kernel ----------
// 512 blocks = m(2) x cd(16 d-chunks of 64) x ce(16 e-ranges of 64); 256 thr.
// Phase 1: v_s[b][dl] = c_attn_b[m,DIM+d] + sum_e h_last[b,e]*Wv[m,e,DIM+d]
//          (recomputed per ce -- redundancy instead of a second dispatch)
// Phase 2: yp[cd][m,b,e] = sum_{d in cd} v_s[b][d-local] * Wp[m,d,e]
__global__ void __launch_bounds__(256) fused_vy(const float* __restrict__ hidden,
                                                const float* __restrict__ c_attn_w,
                                                const float* __restrict__ c_attn_b,
                                                const float* __restrict__ c_proj_w,
                                                float* __restrict__ yp) {
    __shared__ float h_ch[BATCH][256];      // 8 KB: e-chunk of h_last
    __shared__ vfloat4 red[16][16][9];      // 36 KB, reused by both phases
    __shared__ float v_s[BATCH][64];        // 2 KB

    const int tid = threadIdx.x;
    const int ce = blockIdx.x & 15;
    const int cd = (blockIdx.x >> 4) & 15;
    const int m  = blockIdx.x >> 8;

    const int d4 = tid & 15;                // float4 of d within 64-chunk
    const int eg = tid >> 4;                // 16 e-groups

    // ---- Phase 1: v for this (m, cd) ----
    const float* wv = c_attn_w + (size_t)m * DIM * (2 * DIM) + DIM + cd * 64 + d4 * 4;
    vfloat4 acc[BATCH];
#pragma unroll
    for (int b = 0; b < BATCH; ++b) acc[b] = (vfloat4){0.f, 0.f, 0.f, 0.f};

    for (int ch = 0; ch < 4; ++ch) {
        // stage h_last[:, ch*256 .. +256) : 512 float4 by 256 threads
#pragma unroll
        for (int k = 0; k < 2; ++k) {
            int idx = tid + 256 * k;        // 0..511
            int hb = idx >> 6;              // 64 float4 per 256-float row
            int c4 = idx & 63;
            reinterpret_cast<vfloat4*>(h_ch[hb])[c4] =
                reinterpret_cast<const vfloat4*>(
                    hidden + (size_t)hb * (SEQ * DIM) + (size_t)(SEQ - 1) * DIM
                    + ch * 256)[c4];
        }
        __syncthreads();
#pragma unroll
        for (int j = 0; j < 16; ++j) {
            int el = eg * 16 + j;           // 0..255
            int e  = ch * 256 + el;
            vfloat4 w4 = *reinterpret_cast<const vfloat4*>(wv + (size_t)e * (2 * DIM));
#pragma unroll
            for (int b = 0; b < BATCH; ++b) acc[b] += h_ch[b][el] * w4;
        }
        __syncthreads();                    // before next h_ch overwrite
    }

#pragma unroll
    for (int b = 0; b < BATCH; ++b) red[eg][d4][b] = acc[b];
    __syncthreads();

    if (tid < 128) {                        // reduce 16 e-groups + bias -> v_s
        int b = tid >> 4, dq = tid & 15;
        vfloat4 s = red[0][dq][b];
#pragma unroll
        for (int g = 1; g < 16; ++g) s += red[g][dq][b];
        vfloat4 bias = *reinterpret_cast<const vfloat4*>(
            c_attn_b + (size_t)m * 2 * DIM + DIM + cd * 64 + dq * 4);
        reinterpret_cast<vfloat4*>(v_s[b])[dq] = s + bias;
    }
    __syncthreads();

    // ---- Phase 2: yp partial over this 64d x 64e tile ----
    const int e4 = tid & 15;                // float4 of e within 64-e range
    const int dg = tid >> 4;                // 16 d-groups of 4
    const float* wp = c_proj_w + (size_t)m * DIM * DIM + ce * 64 + e4 * 4;

    vfloat4 acc2[BATCH];
#pragma unroll
    for (int b = 0; b < BATCH; ++b) acc2[b] = (vfloat4){0.f, 0.f, 0.f, 0.f};

#pragma unroll
    for (int j = 0; j < 4; ++j) {
        int dl = dg * 4 + j;                // 0..63
        int d  = cd * 64 + dl;
        vfloat4 w4 = *reinterpret_cast<const vfloat4*>(wp + (size_t)d * DIM);
#pragma unroll
        for (int b = 0; b < BATCH; ++b) acc2[b] += v_s[b][dl] * w4;
    }
#pragma unroll
    for (int b = 0; b < BATCH; ++b) red[dg][e4][b] = acc2[b];
    __syncthreads();

    if (tid < 128) {                        // reduce 16 d-groups -> yp
        int b = tid >> 4, eq = tid & 15;
        vfloat4 s = red[0][eq][b];
#pragma unroll
        for (int g = 1; g < 16; ++g) s += red[g][eq][b];
        reinterpret_cast<vfloat4*>(yp)[cd * 4096 + (m * BATCH + b) * 256 + ce * 16 + eq] = s;
    }
}

// ---------- Kernel C (unchanged from R6) ----------
// 2048 blocks: b = bid>>8, q0 = (bid&255)*16; 16 q-rows per block.
__global__ void __launch_bounds__(256) bcast_reduce(const float* __restrict__ yp,
                                                    const float* __restrict__ c_proj_b,
                                                    float* __restrict__ out) {
    int b = blockIdx.x >> 8;
    int q0 = (blockIdx.x & 255) * 16;
    int t = threadIdx.x;                    // e4 = t (256 float4 = 1024 e)

    const vfloat4* bias4 = reinterpret_cast<const vfloat4*>(c_proj_b);
    const vfloat4* yp4 = reinterpret_cast<const vfloat4*>(yp);
    vfloat4 val = bias4[t];
#pragma unroll
    for (int cd = 0; cd < 16; ++cd) {
        val += yp4[cd * 4096 + b * 256 + t];
    }
    if (b == 0) {
        val += bias4[256 + t];
#pragma unroll
        for (int cd = 0; cd < 16; ++cd) {
            val += yp4[cd * 4096 + BATCH * 256 + t];
        }
    }

    vfloat4* o = reinterpret_cast<vfloat4*>(out) + ((size_t)b * QLEN + q0) * 256 + t;
#pragma unroll
    for (int q = 0; q < 16; ++q) {
        __builtin_nontemporal_store(val, o + (size_t)q * 256);
    }
}

extern "C" void kernel_launch(void* const* d_in, const int* in_sizes, int n_in,
                              void* d_out, int out_size, void* d_ws, size_t ws_size,
                              hipStream_t stream) {
    // inputs: encoder_hidden_states, hidden_states, q_w, q_b,
    //         c_attn_w, c_attn_b, c_proj_w, c_proj_b
    const float* hidden   = (const float*)d_in[1];
    const float* c_attn_w = (const float*)d_in[4];
    const float* c_attn_b = (const float*)d_in[5];
    const float* c_proj_w = (const float*)d_in[6];
    const float* c_proj_b = (const float*)d_in[7];
    float* out = (float*)d_out;

    float* yp = (float*)d_ws;               // 16*16384 f32 = 1 MB

    fused_vy<<<512, 256, 0, stream>>>(hidden, c_attn_w, c_attn_b, c_proj_w, yp);
    bcast_reduce<<<2048, 256, 0, stream>>>(yp, c_proj_b, out);
}

// Round 9
// 41.324 us; speedup vs baseline: 1.1741x; 1.0599x over previous
//
#include <hip/hip_runtime.h>

#define DIM    1024
#define BATCH  8
#define QLEN   4096
#define SEQ    128

typedef float vfloat4 __attribute__((ext_vector_type(4)));

// ---------- Kernel A (unchanged from R6) ----------
// grid 512 = m(2) x c(16 d-chunks of 64) x es(16 e-ranges of 64); 256 thr.
// vp[es][m,b,d] = sum_{e in es-range} h_last[b,e] * Wv[m,e,DIM+d]
__global__ void __launch_bounds__(256) kernelA(const float* __restrict__ hidden,
                                               const float* __restrict__ c_attn_w,
                                               float* __restrict__ vp) {
    __shared__ float h_s[BATCH][64];
    __shared__ vfloat4 vred[16][16][9];   // [eg][d4][b] (padded)

    const int tid = threadIdx.x;
    const int es = blockIdx.x & 15;
    const int c  = (blockIdx.x >> 4) & 15;
    const int m  = blockIdx.x >> 8;

    if (tid < 128) {                       // stage h_last[b, es*64 .. +64)
        int b = tid >> 4, e4 = tid & 15;
        const vfloat4* src = reinterpret_cast<const vfloat4*>(
            hidden + (size_t)b * (SEQ * DIM) + (size_t)(SEQ - 1) * DIM + es * 64);
        reinterpret_cast<vfloat4*>(h_s[b])[e4] = src[e4];
    }
    __syncthreads();

    const int d4 = tid & 15;               // float4 of d within chunk
    const int eg = tid >> 4;               // 16 e-groups of 4
    const float* wbase = c_attn_w + (size_t)m * DIM * (2 * DIM) + DIM + c * 64 + d4 * 4;

    vfloat4 acc[BATCH];
#pragma unroll
    for (int b = 0; b < BATCH; ++b) acc[b] = (vfloat4){0.f, 0.f, 0.f, 0.f};

#pragma unroll
    for (int k = 0; k < 4; ++k) {
        int el = eg * 4 + k;               // 0..63
        int e  = es * 64 + el;
        vfloat4 w4 = *reinterpret_cast<const vfloat4*>(wbase + (size_t)e * (2 * DIM));
#pragma unroll
        for (int b = 0; b < BATCH; ++b) acc[b] += h_s[b][el] * w4;
    }
#pragma unroll
    for (int b = 0; b < BATCH; ++b) vred[eg][d4][b] = acc[b];
    __syncthreads();

    if (tid < 128) {                       // reduce 16 e-groups
        int b = tid >> 4, dq = tid & 15;
        vfloat4 s = vred[0][dq][b];
#pragma unroll
        for (int g = 1; g < 16; ++g) s += vred[g][dq][b];
        reinterpret_cast<vfloat4*>(vp)[es * 4096 + (m * BATCH + b) * 256 + c * 16 + dq] = s;
    }
}

// ---------- Kernel B: full-d GEMV -> final y ----------
// grid 512 = m(2) x b(8) x ce(32 e-ranges of 32); 256 thr = dg(32) x e4(8).
// y[m,b,e] = c_proj_b[m,e] + sum_{d=0..1023} v[m,b,d] * Wp[m,d,e]
// where v = c_attn_b[:,DIM:] + sum_es vp  (staged in LDS once per block).
__global__ void __launch_bounds__(256) kernelB(const float* __restrict__ vp,
                                               const float* __restrict__ c_attn_b,
                                               const float* __restrict__ c_proj_w,
                                               const float* __restrict__ c_proj_b,
                                               float* __restrict__ y) {
    __shared__ float v_s[DIM];             // 4 KB
    __shared__ vfloat4 red[32][9];         // [dg][e4] padded

    const int tid = threadIdx.x;
    const int ce = blockIdx.x & 31;        // 32-e range
    const int b  = (blockIdx.x >> 5) & 7;
    const int m  = blockIdx.x >> 8;

    // stage v_s[0..1023] = bias + sum of 16 vp partials (thread = float4 idx)
    {
        vfloat4 s = reinterpret_cast<const vfloat4*>(
            c_attn_b + (size_t)m * 2 * DIM + DIM)[tid];
        const vfloat4* vp4 = reinterpret_cast<const vfloat4*>(vp);
#pragma unroll
        for (int es = 0; es < 16; ++es) {
            s += vp4[es * 4096 + (m * BATCH + b) * 256 + tid];
        }
        reinterpret_cast<vfloat4*>(v_s)[tid] = s;
    }
    __syncthreads();

    const int e4 = tid & 7;                // float4 of e within 32-e range
    const int dg = tid >> 3;               // 32 d-groups
    const float* wp = c_proj_w + (size_t)m * DIM * DIM + ce * 32 + e4 * 4;

    vfloat4 acc = {0.f, 0.f, 0.f, 0.f};
#pragma unroll 8
    for (int j = 0; j < 32; ++j) {
        int d = dg + 32 * j;
        vfloat4 w4 = *reinterpret_cast<const vfloat4*>(wp + (size_t)d * DIM);
        acc += v_s[d] * w4;
    }
    red[dg][e4] = acc;
    __syncthreads();
#pragma unroll
    for (int s = 16; s >= 1; s >>= 1) {
        if (dg < s) red[dg][e4] += red[dg + s][e4];
        __syncthreads();
    }
    if (tid < 8) {                         // final 32 e's = 8 float4, + bias
        vfloat4 bias = reinterpret_cast<const vfloat4*>(c_proj_b)[m * 256 + ce * 8 + tid];
        reinterpret_cast<vfloat4*>(y)[(m * BATCH + b) * 256 + ce * 8 + tid] =
            red[0][tid] + bias;
    }
}

// ---------- Kernel C: pure broadcast store ----------
// 2048 blocks: b = bid>>8, q0 = (bid&255)*16; 16 q-rows per block.
// out[b,q,:] = y[0,b,:] (+ y[1,0,:] if b==0); biases already inside y.
__global__ void __launch_bounds__(256) bcast_kernel(const float* __restrict__ y,
                                                    float* __restrict__ out) {
    int b = blockIdx.x >> 8;
    int q0 = (blockIdx.x & 255) * 16;
    int t = threadIdx.x;                   // e4 = t (256 float4 = 1024 e)

    const vfloat4* y4 = reinterpret_cast<const vfloat4*>(y);
    vfloat4 val = y4[b * 256 + t];
    if (b == 0) {
        val += y4[BATCH * 256 + t];        // m=1, b=0 row
    }

    vfloat4* o = reinterpret_cast<vfloat4*>(out) + ((size_t)b * QLEN + q0) * 256 + t;
#pragma unroll
    for (int q = 0; q < 16; ++q) {
        __builtin_nontemporal_store(val, o + (size_t)q * 256);
    }
}

extern "C" void kernel_launch(void* const* d_in, const int* in_sizes, int n_in,
                              void* d_out, int out_size, void* d_ws, size_t ws_size,
                              hipStream_t stream) {
    // inputs: encoder_hidden_states, hidden_states, q_w, q_b,
    //         c_attn_w, c_attn_b, c_proj_w, c_proj_b
    const float* hidden   = (const float*)d_in[1];
    const float* c_attn_w = (const float*)d_in[4];
    const float* c_attn_b = (const float*)d_in[5];
    const float* c_proj_w = (const float*)d_in[6];
    const float* c_proj_b = (const float*)d_in[7];
    float* out = (float*)d_out;

    float* vp = (float*)d_ws;              // 16*16384 f32 = 1 MB
    float* y  = vp + 16 * 16384;           // 16384 f32 = 64 KB

    kernelA<<<512, 256, 0, stream>>>(hidden, c_attn_w, vp);
    kernelB<<<512, 256, 0, stream>>>(vp, c_attn_b, c_proj_w, c_proj_b, y);
    bcast_kernel<<<2048, 256, 0, stream>>>(y, out);
}

// Round 10
// 39.317 us; speedup vs baseline: 1.2340x; 1.0510x over previous
//
#include <hip/hip_runtime.h>

#define DIM    1024
#define BATCH  8
#define QLEN   4096
#define SEQ    128

typedef float vfloat4 __attribute__((ext_vector_type(4)));

// ---------- Kernel A (unchanged from R6, proven) ----------
// grid 512 = m(2) x c(16 d-chunks of 64) x es(16 e-ranges of 64); 256 thr.
// vp[es][m,b,d] = sum_{e in es-range} h_last[b,e] * Wv[m,e,DIM+d]
// Weights read exactly once; all 8 batches accumulated in registers.
__global__ void __launch_bounds__(256) kernelA(const float* __restrict__ hidden,
                                               const float* __restrict__ c_attn_w,
                                               float* __restrict__ vp) {
    __shared__ float h_s[BATCH][64];
    __shared__ vfloat4 vred[16][16][9];   // [eg][d4][b] (padded)

    const int tid = threadIdx.x;
    const int es = blockIdx.x & 15;
    const int c  = (blockIdx.x >> 4) & 15;
    const int m  = blockIdx.x >> 8;

    if (tid < 128) {                       // stage h_last[b, es*64 .. +64)
        int b = tid >> 4, e4 = tid & 15;
        const vfloat4* src = reinterpret_cast<const vfloat4*>(
            hidden + (size_t)b * (SEQ * DIM) + (size_t)(SEQ - 1) * DIM + es * 64);
        reinterpret_cast<vfloat4*>(h_s[b])[e4] = src[e4];
    }
    __syncthreads();

    const int d4 = tid & 15;               // float4 of d within chunk
    const int eg = tid >> 4;               // 16 e-groups of 4
    const float* wbase = c_attn_w + (size_t)m * DIM * (2 * DIM) + DIM + c * 64 + d4 * 4;

    vfloat4 acc[BATCH];
#pragma unroll
    for (int b = 0; b < BATCH; ++b) acc[b] = (vfloat4){0.f, 0.f, 0.f, 0.f};

#pragma unroll
    for (int k = 0; k < 4; ++k) {
        int el = eg * 4 + k;               // 0..63
        int e  = es * 64 + el;
        vfloat4 w4 = *reinterpret_cast<const vfloat4*>(wbase + (size_t)e * (2 * DIM));
#pragma unroll
        for (int b = 0; b < BATCH; ++b) acc[b] += h_s[b][el] * w4;
    }
#pragma unroll
    for (int b = 0; b < BATCH; ++b) vred[eg][d4][b] = acc[b];
    __syncthreads();

    if (tid < 128) {                       // reduce 16 e-groups
        int b = tid >> 4, dq = tid & 15;
        vfloat4 s = vred[0][dq][b];
#pragma unroll
        for (int g = 1; g < 16; ++g) s += vred[g][dq][b];
        reinterpret_cast<vfloat4*>(vp)[es * 4096 + (m * BATCH + b) * 256 + c * 16 + dq] = s;
    }
}

// ---------- Kernel 2: fused proj-GEMV + broadcast store ----------
// 256 blocks = b(8) x ce(32 e-columns of 32); 256 thr.
// 1) v[m,b,:] = c_attn_b[m,DIM:] + sum_es vp   (LDS; m=1 only when b==0)
// 2) y_tile[e32] = c_proj_b + v · Wp  (b==0 adds the m=1 term)
// 3) stream out[b, q, e-slice] for all q (nontemporal, 128B segments)
__global__ void __launch_bounds__(256) gemv_bcast(const float* __restrict__ vp,
                                                  const float* __restrict__ c_attn_b,
                                                  const float* __restrict__ c_proj_w,
                                                  const float* __restrict__ c_proj_b,
                                                  float* __restrict__ out) {
    __shared__ float v_s[2][DIM];          // 8 KB
    __shared__ vfloat4 red[32][9];         // padded
    __shared__ vfloat4 y_row[8];           // final 32 e's

    const int ce = blockIdx.x & 31;
    const int b  = blockIdx.x >> 5;
    const int t  = threadIdx.x;

    // ---- stage v (m=0; plus m=1 if b==0) ----
    {
        const vfloat4* vp4 = reinterpret_cast<const vfloat4*>(vp);
        vfloat4 s = reinterpret_cast<const vfloat4*>(c_attn_b + DIM)[t];   // m=0 bias
#pragma unroll
        for (int es = 0; es < 16; ++es) s += vp4[es * 4096 + b * 256 + t];
        reinterpret_cast<vfloat4*>(v_s[0])[t] = s;
        if (b == 0) {
            vfloat4 s1 = reinterpret_cast<const vfloat4*>(c_attn_b + 3 * DIM)[t]; // m=1 bias
#pragma unroll
            for (int es = 0; es < 16; ++es) s1 += vp4[es * 4096 + BATCH * 256 + t];
            reinterpret_cast<vfloat4*>(v_s[1])[t] = s1;
        }
    }
    __syncthreads();

    // ---- GEMV tile: 1024 d -> 32 e ----
    const int e4 = t & 7;                  // float4 within 32-e slice
    const int dg = t >> 3;                 // 32 d-groups
    const float* wp0 = c_proj_w + ce * 32 + e4 * 4;
    vfloat4 acc = {0.f, 0.f, 0.f, 0.f};
#pragma unroll 8
    for (int j = 0; j < 32; ++j) {
        int d = dg + 32 * j;
        acc += v_s[0][d] * *reinterpret_cast<const vfloat4*>(wp0 + (size_t)d * DIM);
    }
    if (b == 0) {
        const float* wp1 = c_proj_w + (size_t)DIM * DIM + ce * 32 + e4 * 4;
#pragma unroll 8
        for (int j = 0; j < 32; ++j) {
            int d = dg + 32 * j;
            acc += v_s[1][d] * *reinterpret_cast<const vfloat4*>(wp1 + (size_t)d * DIM);
        }
    }
    red[dg][e4] = acc;
    __syncthreads();

    if (t < 8) {                           // serial reduce of 32 d-groups + bias
        vfloat4 s = red[0][t];
#pragma unroll
        for (int g = 1; g < 32; ++g) s += red[g][t];
        s += reinterpret_cast<const vfloat4*>(c_proj_b)[ce * 8 + t];
        if (b == 0) s += reinterpret_cast<const vfloat4*>(c_proj_b)[256 + ce * 8 + t];
        y_row[t] = s;
    }
    __syncthreads();

    // ---- broadcast store: all 4096 q rows, this 32-e slice ----
    vfloat4 val = y_row[e4];
    const int qs = t >> 3;                 // 0..31
    vfloat4* o = reinterpret_cast<vfloat4*>(out)
               + (size_t)b * QLEN * 256 + ce * 8 + e4;
#pragma unroll 8
    for (int it = 0; it < 128; ++it) {
        int q = it * 32 + qs;
        __builtin_nontemporal_store(val, o + (size_t)q * 256);
    }
}

extern "C" void kernel_launch(void* const* d_in, const int* in_sizes, int n_in,
                              void* d_out, int out_size, void* d_ws, size_t ws_size,
                              hipStream_t stream) {
    // inputs: encoder_hidden_states, hidden_states, q_w, q_b,
    //         c_attn_w, c_attn_b, c_proj_w, c_proj_b
    const float* hidden   = (const float*)d_in[1];
    const float* c_attn_w = (const float*)d_in[4];
    const float* c_attn_b = (const float*)d_in[5];
    const float* c_proj_w = (const float*)d_in[6];
    const float* c_proj_b = (const float*)d_in[7];
    float* out = (float*)d_out;

    float* vp = (float*)d_ws;              // 16*16384 f32 = 1 MB

    kernelA<<<512, 256, 0, stream>>>(hidden, c_attn_w, vp);
    gemv_bcast<<<256, 256, 0, stream>>>(vp, c_attn_b, c_proj_w, c_proj_b, out);
}

// Round 11
// 38.032 us; speedup vs baseline: 1.2757x; 1.0338x over previous
//
#include <hip/hip_runtime.h>

#define DIM    1024
#define BATCH  8
#define QLEN   4096
#define SEQ    128

typedef float vfloat4 __attribute__((ext_vector_type(4)));

// ---------- Kernel A (R6 shape + y bias-init) ----------
// grid 512 = m(2) x c(16 d-chunks of 64) x es(16 e-ranges of 64); 256 thr.
// vp[es][m,b,d] = sum_{e in es-range} h_last[b,e] * Wv[m,e,DIM+d]
// Weights read exactly once; all 8 batches accumulated in registers.
// Blocks with c==0 && es<8 also write y[m*8+es][:] = c_proj_b[m][:].
__global__ void __launch_bounds__(256) kernelA(const float* __restrict__ hidden,
                                               const float* __restrict__ c_attn_w,
                                               const float* __restrict__ c_proj_b,
                                               float* __restrict__ vp,
                                               float* __restrict__ y) {
    __shared__ float h_s[BATCH][64];
    __shared__ vfloat4 vred[16][16][9];   // [eg][d4][b] (padded)

    const int tid = threadIdx.x;
    const int es = blockIdx.x & 15;
    const int c  = (blockIdx.x >> 4) & 15;
    const int m  = blockIdx.x >> 8;

    if (c == 0 && es < BATCH) {            // init y row (m*8+es) with proj bias
        reinterpret_cast<vfloat4*>(y)[(m * BATCH + es) * 256 + tid] =
            reinterpret_cast<const vfloat4*>(c_proj_b)[m * 256 + tid];
    }

    if (tid < 128) {                       // stage h_last[b, es*64 .. +64)
        int b = tid >> 4, e4 = tid & 15;
        const vfloat4* src = reinterpret_cast<const vfloat4*>(
            hidden + (size_t)b * (SEQ * DIM) + (size_t)(SEQ - 1) * DIM + es * 64);
        reinterpret_cast<vfloat4*>(h_s[b])[e4] = src[e4];
    }
    __syncthreads();

    const int d4 = tid & 15;               // float4 of d within chunk
    const int eg = tid >> 4;               // 16 e-groups of 4
    const float* wbase = c_attn_w + (size_t)m * DIM * (2 * DIM) + DIM + c * 64 + d4 * 4;

    vfloat4 acc[BATCH];
#pragma unroll
    for (int b = 0; b < BATCH; ++b) acc[b] = (vfloat4){0.f, 0.f, 0.f, 0.f};

#pragma unroll
    for (int k = 0; k < 4; ++k) {
        int el = eg * 4 + k;               // 0..63
        int e  = es * 64 + el;
        vfloat4 w4 = *reinterpret_cast<const vfloat4*>(wbase + (size_t)e * (2 * DIM));
#pragma unroll
        for (int b = 0; b < BATCH; ++b) acc[b] += h_s[b][el] * w4;
    }
#pragma unroll
    for (int b = 0; b < BATCH; ++b) vred[eg][d4][b] = acc[b];
    __syncthreads();

    if (tid < 128) {                       // reduce 16 e-groups
        int b = tid >> 4, dq = tid & 15;
        vfloat4 s = vred[0][dq][b];
#pragma unroll
        for (int g = 1; g < 16; ++g) s += vred[g][dq][b];
        reinterpret_cast<vfloat4*>(vp)[es * 4096 + (m * BATCH + b) * 256 + c * 16 + dq] = s;
    }
}

// ---------- Kernel B (R6 shape, atomic tail into final y) ----------
// grid 512 = m(2) x cd(16) x ce(16); 256 thr.  Wp tile read ONCE per block.
// y[m,b, ce-range] += sum_{d in cd-chunk} v[m,b,d] * Wp[m,d,e]
// v = c_attn_b[:,DIM:] + sum_es vp.
__global__ void __launch_bounds__(256) kernelB(const float* __restrict__ vp,
                                               const float* __restrict__ c_attn_b,
                                               const float* __restrict__ c_proj_w,
                                               float* __restrict__ y) {
    __shared__ float v_s[BATCH][64];
    __shared__ vfloat4 yred[16][16][9];    // [dg][e4][b] (padded)

    const int tid = threadIdx.x;
    const int ce = blockIdx.x & 15;
    const int cd = (blockIdx.x >> 4) & 15;
    const int m  = blockIdx.x >> 8;

    if (tid < 128) {                       // v_s[b][dl] for this d-chunk
        int b = tid >> 4, d4 = tid & 15;
        vfloat4 s = reinterpret_cast<const vfloat4*>(
            c_attn_b + (size_t)m * 2 * DIM + DIM)[cd * 16 + d4];
        const vfloat4* vp4 = reinterpret_cast<const vfloat4*>(vp);
#pragma unroll
        for (int es = 0; es < 16; ++es) {
            s += vp4[es * 4096 + (m * BATCH + b) * 256 + cd * 16 + d4];
        }
        reinterpret_cast<vfloat4*>(v_s[b])[d4] = s;
    }
    __syncthreads();

    const int e4 = tid & 15;               // float4 of e within 64-e range
    const int dg = tid >> 4;               // 16 d-groups of 4
    const float* wbase = c_proj_w + (size_t)m * DIM * DIM + ce * 64 + e4 * 4;

    vfloat4 acc[BATCH];
#pragma unroll
    for (int b = 0; b < BATCH; ++b) acc[b] = (vfloat4){0.f, 0.f, 0.f, 0.f};

#pragma unroll
    for (int j = 0; j < 4; ++j) {
        int dl = dg * 4 + j;               // 0..63
        int d  = cd * 64 + dl;
        vfloat4 w4 = *reinterpret_cast<const vfloat4*>(wbase + (size_t)d * DIM);
#pragma unroll
        for (int b = 0; b < BATCH; ++b) acc[b] += v_s[b][dl] * w4;
    }
#pragma unroll
    for (int b = 0; b < BATCH; ++b) yred[dg][e4][b] = acc[b];
    __syncthreads();

    if (tid < 128) {                       // reduce 16 d-groups, atomic into y
        int b = tid >> 4, eq = tid & 15;
        vfloat4 s = yred[0][eq][b];
#pragma unroll
        for (int g = 1; g < 16; ++g) s += yred[g][eq][b];
        float* dst = y + (size_t)(m * BATCH + b) * DIM + ce * 64 + eq * 4;
        atomicAdd(dst + 0, s.x);
        atomicAdd(dst + 1, s.y);
        atomicAdd(dst + 2, s.z);
        atomicAdd(dst + 3, s.w);
    }
}

// ---------- Kernel C: pure broadcast, plain stores (R1-proven shape) ----------
// 2048 blocks: b = bid>>8, q0 = (bid&255)*16; 16 contiguous q-rows per block.
// out[b,q,:] = y[0,b,:] (+ y[1,0,:] if b==0); biases already inside y.
__global__ void __launch_bounds__(256) bcast_kernel(const float* __restrict__ y,
                                                    float* __restrict__ out) {
    int b = blockIdx.x >> 8;
    int q0 = (blockIdx.x & 255) * 16;
    int t = threadIdx.x;                   // e4 = t (256 float4 = 1024 e)

    const vfloat4* y4 = reinterpret_cast<const vfloat4*>(y);
    vfloat4 val = y4[b * 256 + t];
    if (b == 0) {
        val += y4[BATCH * 256 + t];        // m=1, b=0 row
    }

    vfloat4* o = reinterpret_cast<vfloat4*>(out) + ((size_t)b * QLEN + q0) * 256 + t;
#pragma unroll
    for (int q = 0; q < 16; ++q) {
        o[(size_t)q * 256] = val;
    }
}

extern "C" void kernel_launch(void* const* d_in, const int* in_sizes, int n_in,
                              void* d_out, int out_size, void* d_ws, size_t ws_size,
                              hipStream_t stream) {
    // inputs: encoder_hidden_states, hidden_states, q_w, q_b,
    //         c_attn_w, c_attn_b, c_proj_w, c_proj_b
    const float* hidden   = (const float*)d_in[1];
    const float* c_attn_w = (const float*)d_in[4];
    const float* c_attn_b = (const float*)d_in[5];
    const float* c_proj_w = (const float*)d_in[6];
    const float* c_proj_b = (const float*)d_in[7];
    float* out = (float*)d_out;

    float* vp = (float*)d_ws;              // 16*16384 f32 = 1 MB
    float* y  = vp + 16 * 16384;           // 16384 f32 = 64 KB

    kernelA<<<512, 256, 0, stream>>>(hidden, c_attn_w, c_proj_b, vp, y);
    kernelB<<<512, 256, 0, stream>>>(vp, c_attn_b, c_proj_w, y);
    bcast_kernel<<<2048, 256, 0, stream>>>(y, out);
}